// Round 10
// baseline (592.968 us; speedup 1.0000x reference)
//
#include <hip/hip_runtime.h>

typedef __attribute__((ext_vector_type(4))) float  f32x4;
typedef __attribute__((ext_vector_type(8))) __bf16 bf16x8;
typedef __attribute__((ext_vector_type(4))) __bf16 bf16x4;

// ---------------------------------------------------------------------------
// prep: qkv/proj weight packing + bias concat + Swin-v2 CPB table, one launch.
//  - W2[((h*6+ft)*8+ks)*64 + l][j] = qw[(ks*32+(l>>4)*8+j)*768 + (h*96+ft*16+(l&15))]
//  - Wp[((h*2+ft)*8+ks)*64 + l][j] = pw[(ks*32+(l>>4)*8+j)*256 + (h*32+ft*16+(l&15))]
//  - bcat = concat(q_bias, 0, v_bias) fp32[768]
//  - cpbias[8][64][64] f32
// ---------------------------------------------------------------------------
__global__ __launch_bounds__(256) void prep_kernel(
    const float* __restrict__ qw, const float* __restrict__ pw,
    const float* __restrict__ qb, const float* __restrict__ vb,
    const float* __restrict__ w1, const float* __restrict__ b1,
    const float* __restrict__ w2,
    __bf16* __restrict__ W2, __bf16* __restrict__ Wp,
    float* __restrict__ bcat, float* __restrict__ cpbias)
{
  if (blockIdx.x < 131) {
    int i = blockIdx.x * 256 + threadIdx.x;
    if (i < 24576) {                       // 8 heads * 6 ft * 8 ks * 64 lanes
      int h = i / 3072, rem = i - h * 3072;
      int ft = rem >> 9, rem2 = rem & 511;
      int ks = rem2 >> 6, l = rem2 & 63;
      int g = l >> 4, c = l & 15;
      int col = h * 96 + ft * 16 + c;
      bf16x8 v;
      #pragma unroll
      for (int j = 0; j < 8; ++j)
        v[j] = (__bf16)qw[(ks * 32 + g * 8 + j) * 768 + col];
      *(bf16x8*)(W2 + (size_t)i * 8) = v;
    } else if (i < 24576 + 8192) {         // 8 heads * 2 ft * 8 ks * 64 lanes
      int j = i - 24576;
      int wv = j >> 10, rem = j & 1023;
      int ft = rem >> 9, rem2 = rem & 511;
      int ks = rem2 >> 6, l = rem2 & 63;
      int g = l >> 4, c = l & 15;
      int col = wv * 32 + ft * 16 + c;
      bf16x8 v;
      #pragma unroll
      for (int j8 = 0; j8 < 8; ++j8)
        v[j8] = (__bf16)pw[(ks * 32 + g * 8 + j8) * 256 + col];
      *(bf16x8*)(Wp + (size_t)j * 8) = v;
    } else if (i < 24576 + 8192 + 768) {
      int cdx = i - 24576 - 8192;
      bcat[cdx] = (cdx < 256) ? qb[cdx] : ((cdx < 512) ? 0.0f : vb[cdx - 512]);
    }
  } else {
    int pair = (blockIdx.x - 131) * 256 + threadIdx.x;   // 4096 pairs (l, m)
    int lq = pair >> 6, mk = pair & 63;
    float d0 = (float)((lq >> 3) - (mk >> 3));
    float d1 = (float)((lq & 7) - (mk & 7));
    float v0 = d0 * (8.0f / 7.0f);
    float v1 = d1 * (8.0f / 7.0f);
    float s0 = (v0 > 0.f) ? 1.f : ((v0 < 0.f) ? -1.f : 0.f);
    float s1 = (v1 > 0.f) ? 1.f : ((v1 < 0.f) ? -1.f : 0.f);
    float r0 = s0 * log2f(fabsf(v0) + 1.0f) * (1.0f / 3.0f);
    float r1 = s1 * log2f(fabsf(v1) + 1.0f) * (1.0f / 3.0f);
    float acc[8] = {0.f, 0.f, 0.f, 0.f, 0.f, 0.f, 0.f, 0.f};
    #pragma unroll 4
    for (int j = 0; j < 512; ++j) {
      float h = fmaxf(r0 * w1[j] + r1 * w1[512 + j] + b1[j], 0.0f);
      #pragma unroll
      for (int q = 0; q < 8; ++q) acc[q] += h * w2[j * 8 + q];
    }
    #pragma unroll
    for (int q = 0; q < 8; ++q) {
      float s = 16.0f / (1.0f + __expf(-acc[q]));
      cpbias[(q * 64 + lq) * 64 + mk] = s;
    }
  }
}

// ---------------------------------------------------------------------------
__device__ __forceinline__ int win_region(int tok, int wi, int wj) {
  int r = tok >> 3, cc = tok & 7;
  int rh = (wi == 15) ? ((r < 4) ? 1 : 2) : 0;
  int rw = (wj == 15) ? ((cc < 4) ? 1 : 2) : 0;
  return rh * 3 + rw;
}

// 2-ft slice of the per-head qkv GEMM: a[ft][tt] += W(FT+ft) @ xs, K=256.
// xf loaded per-tt (4 regs) to keep peak pressure ~32 acc + 12 operand regs.
template <int FT>
__device__ __forceinline__ void qkv2(const __bf16* __restrict__ Wh,
                                     const __bf16* xs, int l, int g, int c,
                                     f32x4 (&a)[2][4])
{
  const f32x4 zz = {0.f, 0.f, 0.f, 0.f};
  #pragma unroll
  for (int ft = 0; ft < 2; ++ft)
    #pragma unroll
    for (int tt = 0; tt < 4; ++tt) a[ft][tt] = zz;
  #pragma unroll
  for (int ks = 0; ks < 8; ++ks) {
    bf16x8 w0 = *(const bf16x8*)(Wh + (size_t)(((FT + 0) * 8 + ks) * 64 + l) * 8);
    bf16x8 w1 = *(const bf16x8*)(Wh + (size_t)(((FT + 1) * 8 + ks) * 64 + l) * 8);
    #pragma unroll
    for (int tt = 0; tt < 4; ++tt) {
      int phys = (ks * 4 + g) ^ (c & 7);
      bf16x8 xf = *(const bf16x8*)&xs[(tt * 16 + c) * 256 + phys * 8];
      a[0][tt] = __builtin_amdgcn_mfma_f32_16x16x32_bf16(w0, xf, a[0][tt], 0, 0, 0);
      a[1][tt] = __builtin_amdgcn_mfma_f32_16x16x32_bf16(w1, xf, a[1][tt], 0, 0, 0);
    }
  }
}

// ---------------------------------------------------------------------------
// Fully fused: qkv-projection + windowed cosine attention + output projection.
// Block = (window, batch), 512 threads = 8 waves, wave = head.
// __launch_bounds__(512, 4): 2nd arg = min waves per EU (gfx950) -> total
// (VGPR+AGPR) budget 128/wave -> with 68 KB LDS, TWO INDEPENDENT blocks/CU.
// Independent blocks desync across barriers (unlike round-9's 16 lockstep
// waves), so one block's MFMA hides the other's LDS/barrier stalls.
//
// K-permutation trick: MFMA sums symmetrically over K; slot (g, j) ->
// k = 16*(j>>2) + 4*g + (j&3) on BOTH operands lets QK fragments pack straight
// from accumulator registers and PV's P-fragment is p[8kp..8kp+7] verbatim.
// Only V needs LDS (true transpose). LDS = 32(xs) + 36(vst) = 68 KB.
// ---------------------------------------------------------------------------
__global__ __launch_bounds__(512, 4) void fused_kernel(
    const float* __restrict__ x, const __bf16* __restrict__ W2,
    const __bf16* __restrict__ Wp, const float* __restrict__ bcat,
    const float* __restrict__ scale, const float* __restrict__ cpb,
    const float* __restrict__ pb, float* __restrict__ outf)
{
  __shared__ __align__(16) __bf16 xs[64 * 256];      // 32 KB: x tile, then O
  __shared__ __align__(16) __bf16 vst[8][64 * 36];   // 36 KB V [tok][unit]
  const f32x4 zz = {0.f, 0.f, 0.f, 0.f};

  int t = threadIdx.x;
  int h = t >> 6, l = t & 63, g = l >> 4, c = l & 15;
  int win = blockIdx.x, b = blockIdx.y;
  int wi = win >> 4, wj = win & 15;
  bool edge = (wi == 15) || (wj == 15);

  // ---- stage x tile (cyclic shift folded into source address) ----
  {
    int r = t >> 3;                      // local token 0..63
    int q8 = t & 7;                      // 32-float chunk of the 256 channels
    int ht = (wi * 8 + (r >> 3) + 4) & 127;
    int wt = (wj * 8 + (r & 7) + 4) & 127;
    const float* src = x + (size_t)((b * 128 + ht) * 128 + wt) * 256 + q8 * 32;
    #pragma unroll
    for (int q = 0; q < 4; ++q) {
      f32x4 a0 = *(const f32x4*)(src + q * 8);
      f32x4 a1 = *(const f32x4*)(src + q * 8 + 4);
      bf16x8 v;
      #pragma unroll
      for (int j = 0; j < 4; ++j) { v[j] = (__bf16)a0[j]; v[4 + j] = (__bf16)a1[j]; }
      int phys = (q8 * 4 + q) ^ (r & 7);
      *(bf16x8*)&xs[r * 256 + phys * 8] = v;
    }
  }
  __syncthreads();

  int toko[4];
  #pragma unroll
  for (int i = 0; i < 4; ++i) {
    int tok = 16 * i + c;
    int ht = (wi * 8 + (tok >> 3) + 4) & 127;
    int wt = (wj * 8 + (tok & 7) + 4) & 127;
    toko[i] = ((b * 128 + ht) * 128 + wt) * 256;
  }

  const __bf16* Wh = W2 + (size_t)h * 24576;
  float ls = __expf(fminf(scale[h], 4.6051701859880914f));  // ln(100)

  // ==== q pass (ft 0,1) -> qB ====
  bf16x8 qB[4], kA[4];
  {
    f32x4 a[2][4];
    qkv2<0>(Wh, xs, l, g, c, a);
    f32x4 b0 = *(const f32x4*)&bcat[h * 96 + 0  + 4 * g];
    f32x4 b1 = *(const f32x4*)&bcat[h * 96 + 16 + 4 * g];
    #pragma unroll
    for (int tt = 0; tt < 4; ++tt) {
      a[0][tt] += b0; a[1][tt] += b1;
      float s = 0.f;
      #pragma unroll
      for (int i = 0; i < 4; ++i)
        s += a[0][tt][i] * a[0][tt][i] + a[1][tt][i] * a[1][tt][i];
      s += __shfl_xor(s, 16); s += __shfl_xor(s, 32);
      float r = rsqrtf(fmaxf(s, 1.55e-5f)) * ls;
      #pragma unroll
      for (int i = 0; i < 4; ++i) {
        qB[tt][i]     = (__bf16)(a[0][tt][i] * r);
        qB[tt][4 + i] = (__bf16)(a[1][tt][i] * r);
      }
    }
  }

  // ==== k pass (ft 2,3) -> kA ====
  {
    f32x4 a[2][4];
    qkv2<2>(Wh, xs, l, g, c, a);
    f32x4 b0 = *(const f32x4*)&bcat[h * 96 + 32 + 4 * g];
    f32x4 b1 = *(const f32x4*)&bcat[h * 96 + 48 + 4 * g];
    #pragma unroll
    for (int tt = 0; tt < 4; ++tt) {
      a[0][tt] += b0; a[1][tt] += b1;
      float s = 0.f;
      #pragma unroll
      for (int i = 0; i < 4; ++i)
        s += a[0][tt][i] * a[0][tt][i] + a[1][tt][i] * a[1][tt][i];
      s += __shfl_xor(s, 16); s += __shfl_xor(s, 32);
      float r = rsqrtf(fmaxf(s, 1.55e-5f));
      #pragma unroll
      for (int i = 0; i < 4; ++i) {
        kA[tt][i]     = (__bf16)(a[0][tt][i] * r);
        kA[tt][4 + i] = (__bf16)(a[1][tt][i] * r);
      }
    }
  }

  // ==== v pass (ft 4,5) -> vst ====
  {
    f32x4 a[2][4];
    qkv2<4>(Wh, xs, l, g, c, a);
    __syncthreads();   // all xs reads done (every wave); xs becomes O buffer
    f32x4 b0 = *(const f32x4*)&bcat[h * 96 + 64 + 4 * g];
    f32x4 b1 = *(const f32x4*)&bcat[h * 96 + 80 + 4 * g];
    #pragma unroll
    for (int tt = 0; tt < 4; ++tt) {
      bf16x4 v0, v1;
      #pragma unroll
      for (int i = 0; i < 4; ++i) {
        v0[i] = (__bf16)(a[0][tt][i] + b0[i]);
        v1[i] = (__bf16)(a[1][tt][i] + b1[i]);
      }
      __bf16* vrow = &vst[h][(tt * 16 + c) * 36];
      *(bf16x4*)&vrow[4 * g]      = v0;
      *(bf16x4*)&vrow[16 + 4 * g] = v1;
    }
  }

  // ---- V^T A-fragments: slot (g,j) -> tok = 32kp + 16*(j>>2) + 4g + (j&3) ----
  bf16x8 va[2][2];   // [mh][kp]
  #pragma unroll
  for (int mh = 0; mh < 2; ++mh)
    #pragma unroll
    for (int kp = 0; kp < 2; ++kp)
      #pragma unroll
      for (int j = 0; j < 8; ++j)
        va[mh][kp][j] =
            vst[h][(32 * kp + 16 * (j >> 2) + 4 * g + (j & 3)) * 36 + 16 * mh + c];

  // ==== QK^T + softmax + PV; O written to xs per q-subtile ====
  #pragma unroll
  for (int nt = 0; nt < 4; ++nt) {
    f32x4 tt4[4];
    #pragma unroll
    for (int mt = 0; mt < 4; ++mt)
      tt4[mt] = __builtin_amdgcn_mfma_f32_16x16x32_bf16(kA[mt], qB[nt], zz, 0, 0, 0);
    int q = nt * 16 + c;
    float p[16];
    #pragma unroll
    for (int mt = 0; mt < 4; ++mt) {
      f32x4 bb = *(const f32x4*)&cpb[(h * 64 + q) * 64 + mt * 16 + 4 * g];
      #pragma unroll
      for (int i = 0; i < 4; ++i) p[mt * 4 + i] = tt4[mt][i] + bb[i];
    }
    if (edge) {
      int regq = win_region(q, wi, wj);
      #pragma unroll
      for (int mt = 0; mt < 4; ++mt)
        #pragma unroll
        for (int i = 0; i < 4; ++i) {
          int k = mt * 16 + 4 * g + i;
          if (win_region(k, wi, wj) != regq) p[mt * 4 + i] -= 100.0f;
        }
    }
    float mx = -1e30f;
    #pragma unroll
    for (int j = 0; j < 16; ++j) mx = fmaxf(mx, p[j]);
    mx = fmaxf(mx, __shfl_xor(mx, 16));
    mx = fmaxf(mx, __shfl_xor(mx, 32));
    float sum = 0.f;
    #pragma unroll
    for (int j = 0; j < 16; ++j) { p[j] = __expf(p[j] - mx); sum += p[j]; }
    sum += __shfl_xor(sum, 16); sum += __shfl_xor(sum, 32);
    float rinv = 1.0f / sum;
    // P fragment for kp is p[8kp..8kp+7] under the same slot permutation
    bf16x8 pf0, pf1;
    #pragma unroll
    for (int j = 0; j < 8; ++j) { pf0[j] = (__bf16)p[j]; pf1[j] = (__bf16)p[8 + j]; }
    #pragma unroll
    for (int mh = 0; mh < 2; ++mh) {
      f32x4 oo = __builtin_amdgcn_mfma_f32_16x16x32_bf16(va[mh][0], pf0, zz, 0, 0, 0);
      oo = __builtin_amdgcn_mfma_f32_16x16x32_bf16(va[mh][1], pf1, oo, 0, 0, 0);
      int chunk = h * 4 + 2 * mh + (g >> 1);     // ch = h*32+16*mh+4*g -> /8
      int tok = nt * 16 + c;
      int phys = chunk ^ (tok & 7);
      bf16x4 ov = { (__bf16)(oo[0] * rinv), (__bf16)(oo[1] * rinv),
                    (__bf16)(oo[2] * rinv), (__bf16)(oo[3] * rinv) };
      *(bf16x4*)&xs[tok * 256 + phys * 8 + 4 * (g & 1)] = ov;
    }
  }
  __syncthreads();   // all O writes visible

  // ==== output projection: C[32 oc][64 tok] = Wp(h) @ O^T ====
  f32x4 acc2[2][4];
  #pragma unroll
  for (int ft = 0; ft < 2; ++ft)
    #pragma unroll
    for (int tt = 0; tt < 4; ++tt) acc2[ft][tt] = zz;

  const __bf16* Wph = Wp + (size_t)h * 8192;
  #pragma unroll
  for (int ks = 0; ks < 8; ++ks) {
    bf16x8 w0 = *(const bf16x8*)(Wph + (size_t)((0 * 8 + ks) * 64 + l) * 8);
    bf16x8 w1 = *(const bf16x8*)(Wph + (size_t)((1 * 8 + ks) * 64 + l) * 8);
    #pragma unroll
    for (int tt = 0; tt < 4; ++tt) {
      int phys = (ks * 4 + g) ^ (c & 7);
      bf16x8 xf = *(const bf16x8*)&xs[(tt * 16 + c) * 256 + phys * 8];
      acc2[0][tt] = __builtin_amdgcn_mfma_f32_16x16x32_bf16(w0, xf, acc2[0][tt], 0, 0, 0);
      acc2[1][tt] = __builtin_amdgcn_mfma_f32_16x16x32_bf16(w1, xf, acc2[1][tt], 0, 0, 0);
    }
  }

  #pragma unroll
  for (int ft = 0; ft < 2; ++ft) {
    f32x4 bb = *(const f32x4*)&pb[h * 32 + ft * 16 + 4 * g];
    #pragma unroll
    for (int tt = 0; tt < 4; ++tt) {
      f32x4 res = acc2[ft][tt] + bb;
      *(f32x4*)&outf[toko[tt] + h * 32 + ft * 16 + 4 * g] = res;
    }
  }
}

// ---------------------------------------------------------------------------
extern "C" void kernel_launch(void* const* d_in, const int* in_sizes, int n_in,
                              void* d_out, int out_size, void* d_ws, size_t ws_size,
                              hipStream_t stream)
{
  const float* x      = (const float*)d_in[0];
  const float* qkv_w  = (const float*)d_in[1];
  const float* q_bias = (const float*)d_in[2];
  const float* v_bias = (const float*)d_in[3];
  const float* scale  = (const float*)d_in[4];
  const float* cpb_w1 = (const float*)d_in[5];
  const float* cpb_b1 = (const float*)d_in[6];
  const float* cpb_w2 = (const float*)d_in[7];
  const float* proj_w = (const float*)d_in[8];
  const float* proj_b = (const float*)d_in[9];

  char* ws = (char*)d_ws;
  // layout (bytes):
  //   [0, 393216)         W2 bf16 packed qkv weights
  //   [393216, 524288)    Wp bf16 packed proj weights
  //   [524288, 527360)    bcat f32[768]
  //   [527360, 658432)    cpb bias f32 [8][64][64]
  __bf16* W2   = (__bf16*)(ws);
  __bf16* Wp   = (__bf16*)(ws + 393216LL);
  float*  bcat = (float*) (ws + 524288LL);
  float*  cpb  = (float*) (ws + 527360LL);

  prep_kernel<<<147, 256, 0, stream>>>(qkv_w, proj_w, q_bias, v_bias,
                                       cpb_w1, cpb_b1, cpb_w2, W2, Wp, bcat, cpb);
  fused_kernel<<<dim3(256, 16), 512, 0, stream>>>(x, W2, Wp, bcat, scale, cpb,
                                                  proj_b, (float*)d_out);
}

// Round 11
// 402.876 us; speedup vs baseline: 1.4718x; 1.4718x over previous
//
#include <hip/hip_runtime.h>

typedef __attribute__((ext_vector_type(4))) float  f32x4;
typedef __attribute__((ext_vector_type(8))) __bf16 bf16x8;
typedef __attribute__((ext_vector_type(4))) __bf16 bf16x4;

// ---------------------------------------------------------------------------
// prep: qkv/proj weight packing + bias concat + Swin-v2 CPB table, one launch.
//  - W2[((h*6+ft)*8+ks)*64 + l][j] = qw[(ks*32+(l>>4)*8+j)*768 + (h*96+ft*16+(l&15))]
//  - Wp[((h*2+ft)*8+ks)*64 + l][j] = pw[(ks*32+(l>>4)*8+j)*256 + (h*32+ft*16+(l&15))]
//  - bcat = concat(q_bias, 0, v_bias) fp32[768]
//  - cpbias[8][64][64] f32
// ---------------------------------------------------------------------------
__global__ __launch_bounds__(256) void prep_kernel(
    const float* __restrict__ qw, const float* __restrict__ pw,
    const float* __restrict__ qb, const float* __restrict__ vb,
    const float* __restrict__ w1, const float* __restrict__ b1,
    const float* __restrict__ w2,
    __bf16* __restrict__ W2, __bf16* __restrict__ Wp,
    float* __restrict__ bcat, float* __restrict__ cpbias)
{
  if (blockIdx.x < 131) {
    int i = blockIdx.x * 256 + threadIdx.x;
    if (i < 24576) {                       // 8 heads * 6 ft * 8 ks * 64 lanes
      int h = i / 3072, rem = i - h * 3072;
      int ft = rem >> 9, rem2 = rem & 511;
      int ks = rem2 >> 6, l = rem2 & 63;
      int g = l >> 4, c = l & 15;
      int col = h * 96 + ft * 16 + c;
      bf16x8 v;
      #pragma unroll
      for (int j = 0; j < 8; ++j)
        v[j] = (__bf16)qw[(ks * 32 + g * 8 + j) * 768 + col];
      *(bf16x8*)(W2 + (size_t)i * 8) = v;
    } else if (i < 24576 + 8192) {         // 8 heads * 2 ft * 8 ks * 64 lanes
      int j = i - 24576;
      int wv = j >> 10, rem = j & 1023;
      int ft = rem >> 9, rem2 = rem & 511;
      int ks = rem2 >> 6, l = rem2 & 63;
      int g = l >> 4, c = l & 15;
      int col = wv * 32 + ft * 16 + c;
      bf16x8 v;
      #pragma unroll
      for (int j8 = 0; j8 < 8; ++j8)
        v[j8] = (__bf16)pw[(ks * 32 + g * 8 + j8) * 256 + col];
      *(bf16x8*)(Wp + (size_t)j * 8) = v;
    } else if (i < 24576 + 8192 + 768) {
      int cdx = i - 24576 - 8192;
      bcat[cdx] = (cdx < 256) ? qb[cdx] : ((cdx < 512) ? 0.0f : vb[cdx - 512]);
    }
  } else {
    int pair = (blockIdx.x - 131) * 256 + threadIdx.x;   // 4096 pairs (l, m)
    int lq = pair >> 6, mk = pair & 63;
    float d0 = (float)((lq >> 3) - (mk >> 3));
    float d1 = (float)((lq & 7) - (mk & 7));
    float v0 = d0 * (8.0f / 7.0f);
    float v1 = d1 * (8.0f / 7.0f);
    float s0 = (v0 > 0.f) ? 1.f : ((v0 < 0.f) ? -1.f : 0.f);
    float s1 = (v1 > 0.f) ? 1.f : ((v1 < 0.f) ? -1.f : 0.f);
    float r0 = s0 * log2f(fabsf(v0) + 1.0f) * (1.0f / 3.0f);
    float r1 = s1 * log2f(fabsf(v1) + 1.0f) * (1.0f / 3.0f);
    float acc[8] = {0.f, 0.f, 0.f, 0.f, 0.f, 0.f, 0.f, 0.f};
    #pragma unroll 4
    for (int j = 0; j < 512; ++j) {
      float h = fmaxf(r0 * w1[j] + r1 * w1[512 + j] + b1[j], 0.0f);
      #pragma unroll
      for (int q = 0; q < 8; ++q) acc[q] += h * w2[j * 8 + q];
    }
    #pragma unroll
    for (int q = 0; q < 8; ++q) {
      float s = 16.0f / (1.0f + __expf(-acc[q]));
      cpbias[(q * 64 + lq) * 64 + mk] = s;
    }
  }
}

// ---------------------------------------------------------------------------
__device__ __forceinline__ int win_region(int tok, int wi, int wj) {
  int r = tok >> 3, cc = tok & 7;
  int rh = (wi == 15) ? ((r < 4) ? 1 : 2) : 0;
  int rw = (wj == 15) ? ((cc < 4) ? 1 : 2) : 0;
  return rh * 3 + rw;
}

// ---------------------------------------------------------------------------
// Fully fused qkv + windowed cosine attention + output projection.
// Block = window, 1024 threads = 16 waves, wave = (head, q-half of 32 tokens)
// (the split-head design that fits the 128-total-reg bucket -> 16 waves/CU).
// This round: the q/k/v GEMM is ONE merged 6-ft pass (48 acc regs, 12
// independent MFMA chains per k-step, single xs sweep), and V is staged
// TRANSPOSED ([unit][tok]) so PV A-fragments are vector bf16x4 LDS reads
// instead of 32 scalar u16 reads.
// K-permutation trick: slot (g,j) -> k = 16*(j>>2)+4g+(j&3) on both MFMA
// operands; QK fragments pack from accumulators, P-fragment is p[8kp..8kp+7].
// LDS = xs 32 KB + kst 36 KB + vstT 36 KB = 104 KB.
// ---------------------------------------------------------------------------
__global__ __launch_bounds__(1024, 1) void fused_kernel(
    const float* __restrict__ x, const __bf16* __restrict__ W2,
    const __bf16* __restrict__ Wp, const float* __restrict__ bcat,
    const float* __restrict__ scale, const float* __restrict__ cpb,
    const float* __restrict__ pb, float* __restrict__ outf)
{
  __shared__ __align__(16) __bf16 xs[64 * 256];       // 32 KB: x tile, then O
  __shared__ __align__(16) __bf16 kst[8][64 * 36];    // 36 KB Kn [tok][unit]
  __shared__ __align__(16) __bf16 vstT[8][32 * 72];   // 36 KB V^T [unit][tok]
  const f32x4 zz = {0.f, 0.f, 0.f, 0.f};

  int t = threadIdx.x;
  int wv = t >> 6, h = wv >> 1, hf = wv & 1;
  int l = t & 63, g = l >> 4, c = l & 15;
  int win = blockIdx.x, b = blockIdx.y;
  int wi = win >> 4, wj = win & 15;
  bool edge = (wi == 15) || (wj == 15);

  // ---- stage x tile (cyclic shift folded into source address) ----
  {
    int r = t >> 4;                      // token 0..63
    int sub = t & 15;                    // 16 threads/token, 16 ch each
    int ht = (wi * 8 + (r >> 3) + 4) & 127;
    int wt = (wj * 8 + (r & 7) + 4) & 127;
    const float* src = x + (size_t)((b * 128 + ht) * 128 + wt) * 256 + sub * 16;
    #pragma unroll
    for (int q = 0; q < 2; ++q) {
      f32x4 a0 = *(const f32x4*)(src + q * 8);
      f32x4 a1 = *(const f32x4*)(src + q * 8 + 4);
      bf16x8 v;
      #pragma unroll
      for (int j = 0; j < 4; ++j) { v[j] = (__bf16)a0[j]; v[4 + j] = (__bf16)a1[j]; }
      int phys = (sub * 2 + q) ^ (r & 7);
      *(bf16x8*)&xs[r * 256 + phys * 8] = v;
    }
  }
  __syncthreads();

  int toko[2];
  #pragma unroll
  for (int ntl = 0; ntl < 2; ++ntl) {
    int tok = (2 * hf + ntl) * 16 + c;
    int ht = (wi * 8 + (tok >> 3) + 4) & 127;
    int wt = (wj * 8 + (tok & 7) + 4) & 127;
    toko[ntl] = ((b * 128 + ht) * 128 + wt) * 256;
  }

  const __bf16* Wh = W2 + (size_t)h * 24576;
  float ls = __expf(fminf(scale[h], 4.6051701859880914f));  // ln(100)

  // ==== merged qkv GEMM: a[ft 0..5][ntl] over K=256 (one xs sweep) ====
  f32x4 a[6][2];
  #pragma unroll
  for (int ft = 0; ft < 6; ++ft)
    #pragma unroll
    for (int ntl = 0; ntl < 2; ++ntl) a[ft][ntl] = zz;

  #pragma unroll
  for (int ks = 0; ks < 8; ++ks) {
    bf16x8 w[6];
    #pragma unroll
    for (int ft = 0; ft < 6; ++ft)
      w[ft] = *(const bf16x8*)(Wh + (size_t)((ft * 8 + ks) * 64 + l) * 8);
    #pragma unroll
    for (int ntl = 0; ntl < 2; ++ntl) {
      int phys = (ks * 4 + g) ^ (c & 7);
      bf16x8 xf = *(const bf16x8*)&xs[((2 * hf + ntl) * 16 + c) * 256 + phys * 8];
      #pragma unroll
      for (int ft = 0; ft < 6; ++ft)
        a[ft][ntl] = __builtin_amdgcn_mfma_f32_16x16x32_bf16(w[ft], xf, a[ft][ntl], 0, 0, 0);
    }
  }

  // ==== epilogue: bias, l2-norms, pack qB, stage k and V^T ====
  bf16x8 qB[2];
  {
    f32x4 bq0 = *(const f32x4*)&bcat[h * 96 + 0  + 4 * g];
    f32x4 bq1 = *(const f32x4*)&bcat[h * 96 + 16 + 4 * g];
    f32x4 bk0 = *(const f32x4*)&bcat[h * 96 + 32 + 4 * g];
    f32x4 bk1 = *(const f32x4*)&bcat[h * 96 + 48 + 4 * g];
    f32x4 bv0 = *(const f32x4*)&bcat[h * 96 + 64 + 4 * g];
    f32x4 bv1 = *(const f32x4*)&bcat[h * 96 + 80 + 4 * g];
    #pragma unroll
    for (int ntl = 0; ntl < 2; ++ntl) {
      int tok = (2 * hf + ntl) * 16 + c;
      a[0][ntl] += bq0; a[1][ntl] += bq1;
      a[2][ntl] += bk0; a[3][ntl] += bk1;
      // q normalize * logit scale -> registers
      float sq = 0.f, sk = 0.f;
      #pragma unroll
      for (int i = 0; i < 4; ++i) {
        sq += a[0][ntl][i] * a[0][ntl][i] + a[1][ntl][i] * a[1][ntl][i];
        sk += a[2][ntl][i] * a[2][ntl][i] + a[3][ntl][i] * a[3][ntl][i];
      }
      sq += __shfl_xor(sq, 16); sq += __shfl_xor(sq, 32);
      sk += __shfl_xor(sk, 16); sk += __shfl_xor(sk, 32);
      float rq = rsqrtf(fmaxf(sq, 1.55e-5f)) * ls;
      float rk = rsqrtf(fmaxf(sk, 1.55e-5f));
      bf16x4 k0, k1;
      #pragma unroll
      for (int i = 0; i < 4; ++i) {
        qB[ntl][i]     = (__bf16)(a[0][ntl][i] * rq);
        qB[ntl][4 + i] = (__bf16)(a[1][ntl][i] * rq);
        k0[i] = (__bf16)(a[2][ntl][i] * rk);
        k1[i] = (__bf16)(a[3][ntl][i] * rk);
      }
      *(bf16x4*)&kst[h][tok * 36 + 4 * g]      = k0;
      *(bf16x4*)&kst[h][tok * 36 + 16 + 4 * g] = k1;
      // V^T stage: vstT[unit][tok]
      #pragma unroll
      for (int i = 0; i < 4; ++i) {
        vstT[h][(4 * g + i) * 72 + tok]      = (__bf16)(a[4][ntl][i] + bv0[i]);
        vstT[h][(16 + 4 * g + i) * 72 + tok] = (__bf16)(a[5][ntl][i] + bv1[i]);
      }
    }
  }
  __syncthreads();   // kst/vstT visible; all xs reads done (xs becomes O)

  // ---- K A-fragments: slot (g,j) -> unit = 16*(j>>2)+4g+(j&3), tok = 16mt+c
  bf16x8 kA[4];
  #pragma unroll
  for (int mt = 0; mt < 4; ++mt) {
    bf16x4 lo = *(const bf16x4*)&kst[h][(mt * 16 + c) * 36 + 4 * g];
    bf16x4 hi = *(const bf16x4*)&kst[h][(mt * 16 + c) * 36 + 16 + 4 * g];
    #pragma unroll
    for (int i = 0; i < 4; ++i) { kA[mt][i] = lo[i]; kA[mt][4 + i] = hi[i]; }
  }
  // ---- V^T A-fragments from vstT: unit = 16mh + c, tok slot (g,j) ----
  bf16x8 va[2][2];   // [mh][kp]
  #pragma unroll
  for (int mh = 0; mh < 2; ++mh)
    #pragma unroll
    for (int kp = 0; kp < 2; ++kp) {
      bf16x4 lo = *(const bf16x4*)&vstT[h][(16 * mh + c) * 72 + 32 * kp + 4 * g];
      bf16x4 hi = *(const bf16x4*)&vstT[h][(16 * mh + c) * 72 + 32 * kp + 16 + 4 * g];
      #pragma unroll
      for (int i = 0; i < 4; ++i) { va[mh][kp][i] = lo[i]; va[mh][kp][4 + i] = hi[i]; }
    }

  // ==== QK^T + softmax + PV for this wave's 2 q-subtiles; O -> xs ====
  #pragma unroll
  for (int ntl = 0; ntl < 2; ++ntl) {
    f32x4 tt4[4];
    #pragma unroll
    for (int mt = 0; mt < 4; ++mt)
      tt4[mt] = __builtin_amdgcn_mfma_f32_16x16x32_bf16(kA[mt], qB[ntl], zz, 0, 0, 0);
    int q = (2 * hf + ntl) * 16 + c;
    float p[16];
    #pragma unroll
    for (int mt = 0; mt < 4; ++mt) {
      f32x4 bb = *(const f32x4*)&cpb[(h * 64 + q) * 64 + mt * 16 + 4 * g];
      #pragma unroll
      for (int i = 0; i < 4; ++i) p[mt * 4 + i] = tt4[mt][i] + bb[i];
    }
    if (edge) {
      int regq = win_region(q, wi, wj);
      #pragma unroll
      for (int mt = 0; mt < 4; ++mt)
        #pragma unroll
        for (int i = 0; i < 4; ++i) {
          int k = mt * 16 + 4 * g + i;
          if (win_region(k, wi, wj) != regq) p[mt * 4 + i] -= 100.0f;
        }
    }
    float mx = -1e30f;
    #pragma unroll
    for (int j = 0; j < 16; ++j) mx = fmaxf(mx, p[j]);
    mx = fmaxf(mx, __shfl_xor(mx, 16));
    mx = fmaxf(mx, __shfl_xor(mx, 32));
    float sum = 0.f;
    #pragma unroll
    for (int j = 0; j < 16; ++j) { p[j] = __expf(p[j] - mx); sum += p[j]; }
    sum += __shfl_xor(sum, 16); sum += __shfl_xor(sum, 32);
    float rinv = 1.0f / sum;
    // P fragment for kp is p[8kp..8kp+7] under the same slot permutation
    bf16x8 pf0, pf1;
    #pragma unroll
    for (int j = 0; j < 8; ++j) { pf0[j] = (__bf16)p[j]; pf1[j] = (__bf16)p[8 + j]; }
    int tok = q;
    #pragma unroll
    for (int mh = 0; mh < 2; ++mh) {
      f32x4 oo = __builtin_amdgcn_mfma_f32_16x16x32_bf16(va[mh][0], pf0, zz, 0, 0, 0);
      oo = __builtin_amdgcn_mfma_f32_16x16x32_bf16(va[mh][1], pf1, oo, 0, 0, 0);
      int chunk = h * 4 + 2 * mh + (g >> 1);     // ch = h*32+16*mh+4*g -> /8
      int phys = chunk ^ (tok & 7);
      bf16x4 ov = { (__bf16)(oo[0] * rinv), (__bf16)(oo[1] * rinv),
                    (__bf16)(oo[2] * rinv), (__bf16)(oo[3] * rinv) };
      *(bf16x4*)&xs[tok * 256 + phys * 8 + 4 * (g & 1)] = ov;
    }
  }
  __syncthreads();   // all O writes visible

  // ==== output projection: C[32 oc][32 tok] = Wp(h) @ O^T (this half) ====
  f32x4 acc2[2][2];
  #pragma unroll
  for (int ft = 0; ft < 2; ++ft)
    #pragma unroll
    for (int ntl = 0; ntl < 2; ++ntl) acc2[ft][ntl] = zz;

  const __bf16* Wph = Wp + (size_t)h * 8192;
  #pragma unroll
  for (int ks = 0; ks < 8; ++ks) {
    bf16x8 w0 = *(const bf16x8*)(Wph + (size_t)((0 * 8 + ks) * 64 + l) * 8);
    bf16x8 w1 = *(const bf16x8*)(Wph + (size_t)((1 * 8 + ks) * 64 + l) * 8);
    #pragma unroll
    for (int ntl = 0; ntl < 2; ++ntl) {
      int tok = (2 * hf + ntl) * 16 + c;
      int phys = (ks * 4 + g) ^ (c & 7);
      bf16x8 xf = *(const bf16x8*)&xs[tok * 256 + phys * 8];
      acc2[0][ntl] = __builtin_amdgcn_mfma_f32_16x16x32_bf16(w0, xf, acc2[0][ntl], 0, 0, 0);
      acc2[1][ntl] = __builtin_amdgcn_mfma_f32_16x16x32_bf16(w1, xf, acc2[1][ntl], 0, 0, 0);
    }
  }

  #pragma unroll
  for (int ft = 0; ft < 2; ++ft) {
    f32x4 bb = *(const f32x4*)&pb[h * 32 + ft * 16 + 4 * g];
    #pragma unroll
    for (int ntl = 0; ntl < 2; ++ntl) {
      f32x4 res = acc2[ft][ntl] + bb;
      *(f32x4*)&outf[toko[ntl] + h * 32 + ft * 16 + 4 * g] = res;
    }
  }
}

// ---------------------------------------------------------------------------
extern "C" void kernel_launch(void* const* d_in, const int* in_sizes, int n_in,
                              void* d_out, int out_size, void* d_ws, size_t ws_size,
                              hipStream_t stream)
{
  const float* x      = (const float*)d_in[0];
  const float* qkv_w  = (const float*)d_in[1];
  const float* q_bias = (const float*)d_in[2];
  const float* v_bias = (const float*)d_in[3];
  const float* scale  = (const float*)d_in[4];
  const float* cpb_w1 = (const float*)d_in[5];
  const float* cpb_b1 = (const float*)d_in[6];
  const float* cpb_w2 = (const float*)d_in[7];
  const float* proj_w = (const float*)d_in[8];
  const float* proj_b = (const float*)d_in[9];

  char* ws = (char*)d_ws;
  // layout (bytes):
  //   [0, 393216)         W2 bf16 packed qkv weights
  //   [393216, 524288)    Wp bf16 packed proj weights
  //   [524288, 527360)    bcat f32[768]
  //   [527360, 658432)    cpb bias f32 [8][64][64]
  __bf16* W2   = (__bf16*)(ws);
  __bf16* Wp   = (__bf16*)(ws + 393216LL);
  float*  bcat = (float*) (ws + 524288LL);
  float*  cpb  = (float*) (ws + 527360LL);

  prep_kernel<<<147, 256, 0, stream>>>(qkv_w, proj_w, q_bias, v_bias,
                                       cpb_w1, cpb_b1, cpb_w2, W2, Wp, bcat, cpb);
  fused_kernel<<<dim3(256, 16), 1024, 0, stream>>>(x, W2, Wp, bcat, scale, cpb,
                                                   proj_b, (float*)d_out);
}